// Round 15
// baseline (2070.511 us; speedup 1.0000x reference)
//
#include <hip/hip_runtime.h>
#include <hip/hip_bf16.h>

#define T_DIM 256
#define B_DIM 256
#define E_DIM 256
#define H_DIM 512
#define V_DIM 50257
#define BH    (B_DIM * H_DIM)          // elems per h slot
#define PRE_AHEAD 5                    // at step t, arm slot t+5
#define SENT  0x7F7F7F7Fu              // bf16 |h|<=1 can never be 0x7F7F

typedef __attribute__((ext_vector_type(8))) short short8;
typedef __attribute__((ext_vector_type(4))) float f32x4;
typedef __attribute__((ext_vector_type(4))) unsigned int uint4v;
typedef __attribute__((ext_vector_type(2))) unsigned int uint2v;

#define MFMA __builtin_amdgcn_mfma_f32_16x16x32_bf16

__device__ __forceinline__ unsigned short f2bf(float f) {
    union { float f; unsigned u; } v; v.f = f;
    unsigned r = v.u + 0x7FFFu + ((v.u >> 16) & 1u);
    return (unsigned short)(r >> 16);
}
__device__ __forceinline__ short cvt_bf(float f) { return (short)f2bf(f); }
__device__ __forceinline__ float sigmoidf_(float x) {
    return 1.0f / (1.0f + __expf(-x));
}
__device__ __forceinline__ float tanhf_(float x) {
    float xc = fminf(fmaxf(x, -15.0f), 15.0f);
    float e = __expf(2.0f * xc);
    return (e - 1.0f) / (e + 1.0f);
}

// Sweep discipline (R14-proven): first pass = C++ cached loads (L2-deduped,
// compiler-counted waits); escalation = asm sc0 sc1 (MALL truth) for pending
// fragments only -> correctness/liveness placement-independent. Stores/arms
// = asm sc0 sc1 (MALL commit). Write-once slots + sentinel make cached
// first reads safe (sentinel-or-final-data, never stale).
__device__ __forceinline__ short8 load16_mall(const unsigned short* p) {
    short8 r;
    asm volatile("global_load_dwordx4 %0, %1, off sc0 sc1"
                 : "=v"(r) : "v"(p) : "memory");
    return r;
}
__device__ __forceinline__ void store8_mall(unsigned short* p, uint2v v) {
    asm volatile("global_store_dwordx2 %0, %1, off sc0 sc1"
                 :: "v"(p), "v"(v) : "memory");
}
__device__ __forceinline__ bool frag_ready(short8 v) {
    union { short8 s; uint4v u; } c; c.s = v;
    return (c.u[0] != SENT) & (c.u[1] != SENT) & (c.u[2] != SENT) & (c.u[3] != SENT);
}

// Escalation loop: asm MALL re-load of pending fragments until sentinel-free.
__device__ __forceinline__ void sweep_converge(short8 (&hfr)[16],
                                               const unsigned short* hr)
{
    unsigned pend = 0;
    #pragma unroll
    for (int k = 0; k < 16; ++k)
        pend |= frag_ready(hfr[k]) ? 0u : (1u << k);
    #pragma unroll 1
    while (!__all(pend == 0)) {
        #pragma unroll
        for (int k = 0; k < 16; ++k)
            if (pend & (1u << k)) hfr[k] = load16_mall(hr + k * 32);
        asm volatile("s_waitcnt vmcnt(0)" ::: "memory");
        __builtin_amdgcn_sched_barrier(0);
        unsigned np = 0;
        #pragma unroll
        for (int k = 0; k < 16; ++k)
            if (pend & (1u << k))
                np |= frag_ready(hfr[k]) ? 0u : (1u << k);
        pend = np;
    }
    __builtin_amdgcn_sched_barrier(0);
}

// ---------------- LSTM persistent kernel ----------------
// 256 blocks, 1/CU (48 KiB LDS). Tiling: hg = blk&63 (8 hidden cols),
// pair = blk>>6 (0..3) -> TWO independent recurrence chains per block:
// bgA = pair (rows 32p..+31), bgB = pair+4. The W slice depends only on hg,
// so one LDS copy serves both chains. Per step the chains are interleaved so
// each chain's sweep RTT hides under the other's compute (R14 had all
// latency exposed serially). Narrow-tile mapping (2 N-tiles: n0 = gates i|j,
// n1 = f|o; lane owns 1 row x 4 hcols x 2 gates; shfl_xor(32) completes the
// gate set) is R13-correctness-proven. Sentinel protocol is R8/R14-proven.
__global__ void __launch_bounds__(128, 1)
lstm_persist(const float* __restrict__ x,
             const float* __restrict__ wk,
             const float* __restrict__ bias,
             unsigned short* __restrict__ hbuf)   // [T+1][B][H] bf16
{
    extern __shared__ unsigned short lds_w[];     // [48 frag][64 lane][8]
    const int tid = threadIdx.x;
    const int blk = blockIdx.x;
    const int hg  = blk & 63;
    const int pr  = blk >> 6;                     // 0..3
    const int hh  = hg * 8;

    // ---- preload weights into LDS as W^T fragments (once) ----
    // frag f = kt*2+n; lane l (c16=l&15); elem j:
    //   k = kt*32+(l>>4)*8+j, col = (n*2+(c16>>3))*512 + hh + (c16&7)
    for (int f = 0; f < 48; ++f) {
        const int kt = f >> 1, n = f & 1;
        for (int idx = tid; idx < 512; idx += 128) {
            const int l   = idx & 63;
            const int j   = idx >> 6;
            const int c16 = l & 15;
            const int k   = kt * 32 + (l >> 4) * 8 + j;
            const int col = (n * 2 + (c16 >> 3)) * 512 + hh + (c16 & 7);
            lds_w[(f * 64 + l) * 8 + j] = f2bf(wk[(size_t)k * 2048 + col]);
        }
    }
    __syncthreads();

    const int w    = tid >> 6;        // wave: rows [bb + w*16, +16) per chain
    const int lane = tid & 63;
    const int lc   = lane & 15;
    const int lk   = lane >> 4;
    const int hb4  = (lk & 1) * 4;    // lane's hcol base (0 or 4)
    const bool glo = (lane & 32) == 0;  // holds gates {i,f}; partner {j,o}

    const f32x4 bi  = *(const f32x4*)(bias + 0 * 512 + hh + hb4);
    const f32x4 bj  = *(const f32x4*)(bias + 1 * 512 + hh + hb4);
    f32x4       bf_ = *(const f32x4*)(bias + 2 * 512 + hh + hb4);
    const f32x4 bo  = *(const f32x4*)(bias + 3 * 512 + hh + hb4);
    bf_ = bf_ + 1.0f;                                  // FORGET_BIAS

    const int arowA = pr * 32       + w * 16 + lc;     // chain A batch row
    const int arowB = (pr + 4) * 32 + w * 16 + lc;     // chain B batch row
    const float* xrowA = x + (size_t)arowA * E_DIM + lk * 8;
    const float* xrowB = x + (size_t)arowB * E_DIM + lk * 8;
    const size_t hroA = (size_t)arowA * H_DIM + lk * 8;
    const size_t hroB = (size_t)arowB * H_DIM + lk * 8;
    const size_t hsoA = (size_t)arowA * H_DIM + hh + hb4;
    const size_t hsoB = (size_t)arowB * H_DIM + hh + hb4;

    f32x4 cA = {0.f,0.f,0.f,0.f}, cB = cA;

    // ---- x_0 for both chains ----
    f32x4 xregA[16], xregB[16];
    #pragma unroll
    for (int k = 0; k < 8; ++k) {
        xregA[2*k]   = *(const f32x4*)(xrowA + k * 32);
        xregA[2*k+1] = *(const f32x4*)(xrowA + k * 32 + 4);
        xregB[2*k]   = *(const f32x4*)(xrowB + k * 32);
        xregB[2*k+1] = *(const f32x4*)(xrowB + k * 32 + 4);
    }

    const uint2v sentv = {SENT, SENT};

    for (int t = 0; t < T_DIM; ++t) {
        const unsigned short* hrA = hbuf + (size_t)t * BH + hroA;
        const unsigned short* hrB = hbuf + (size_t)t * BH + hroB;
        short8 hfrA[16], hfrB[16];

        // ---- P1: chain A x-part MFMA (regs resident) ----
        f32x4 aA0 = {0.f,0.f,0.f,0.f}, aA1 = aA0;
        #pragma unroll
        for (int kt = 0; kt < 8; ++kt) {
            const f32x4 lo = xregA[2*kt], hi = xregA[2*kt+1];
            short8 a;
            a[0]=cvt_bf(lo[0]); a[1]=cvt_bf(lo[1]); a[2]=cvt_bf(lo[2]); a[3]=cvt_bf(lo[3]);
            a[4]=cvt_bf(hi[0]); a[5]=cvt_bf(hi[1]); a[6]=cvt_bf(hi[2]); a[7]=cvt_bf(hi[3]);
            const unsigned short* wp = lds_w + ((size_t)(kt * 2) * 64 + lane) * 8;
            aA0 = MFMA(*(const short8*)(wp +   0), a, aA0, 0,0,0);
            aA1 = MFMA(*(const short8*)(wp + 512), a, aA1, 0,0,0);
        }

        // ---- P2: issue sweep A (pinned after P1 by sched_barrier) ----
        if (t > 0) {
            __builtin_amdgcn_sched_barrier(0);
            #pragma unroll
            for (int k = 0; k < 16; ++k)
                hfrA[k] = *(const short8*)(hrA + k * 32);
        }

        // ---- P3: chain B x-part MFMA (hides sweep A RTT) ----
        f32x4 aB0 = {0.f,0.f,0.f,0.f}, aB1 = aB0;
        #pragma unroll
        for (int kt = 0; kt < 8; ++kt) {
            const f32x4 lo = xregB[2*kt], hi = xregB[2*kt+1];
            short8 a;
            a[0]=cvt_bf(lo[0]); a[1]=cvt_bf(lo[1]); a[2]=cvt_bf(lo[2]); a[3]=cvt_bf(lo[3]);
            a[4]=cvt_bf(hi[0]); a[5]=cvt_bf(hi[1]); a[6]=cvt_bf(hi[2]); a[7]=cvt_bf(hi[3]);
            const unsigned short* wp = lds_w + ((size_t)(kt * 2) * 64 + lane) * 8;
            aB0 = MFMA(*(const short8*)(wp +   0), a, aB0, 0,0,0);
            aB1 = MFMA(*(const short8*)(wp + 512), a, aB1, 0,0,0);
        }

        if (t > 0) {
            // ---- P4: converge sweep A (compiler-counted wait + escalate) ----
            sweep_converge(hfrA, hrA);
            // ---- P5: chain A h-part MFMA ----
            #pragma unroll
            for (int k = 0; k < 16; ++k) {
                const unsigned short* wp = lds_w + ((size_t)((8 + k) * 2) * 64 + lane) * 8;
                aA0 = MFMA(*(const short8*)(wp +   0), hfrA[k], aA0, 0,0,0);
                aA1 = MFMA(*(const short8*)(wp + 512), hfrA[k], aA1, 0,0,0);
            }
            // ---- P6: issue sweep B (pinned late) ----
            __builtin_amdgcn_sched_barrier(0);
            #pragma unroll
            for (int k = 0; k < 16; ++k)
                hfrB[k] = *(const short8*)(hrB + k * 32);
        }

        // ---- P6.5: x prefetch for t+1, both chains (in flight across
        //            updateA / sweepB drain / h-MFMA_B) ----
        if (t + 1 < T_DIM) {
            const float* xnA = xrowA + (size_t)(t + 1) * (B_DIM * E_DIM);
            const float* xnB = xrowB + (size_t)(t + 1) * (B_DIM * E_DIM);
            #pragma unroll
            for (int k = 0; k < 8; ++k) {
                xregA[2*k]   = *(const f32x4*)(xnA + k * 32);
                xregA[2*k+1] = *(const f32x4*)(xnA + k * 32 + 4);
                xregB[2*k]   = *(const f32x4*)(xnB + k * 32);
                xregB[2*k+1] = *(const f32x4*)(xnB + k * 32 + 4);
            }
        }

        // ---- P7: chain A update + fire-and-forget store/arm ----
        {
            f32x4 p0, p1;
            #pragma unroll
            for (int j = 0; j < 4; ++j) {
                p0[j] = __shfl_xor(aA0[j], 32);
                p1[j] = __shfl_xor(aA1[j], 32);
            }
            unsigned short hu[4];
            #pragma unroll
            for (int j = 0; j < 4; ++j) {
                const float iv = (glo ? aA0[j] : p0[j]) + bi[j];
                const float jv = (glo ? p0[j] : aA0[j]) + bj[j];
                const float fv = (glo ? aA1[j] : p1[j]) + bf_[j];
                const float ov = (glo ? p1[j] : aA1[j]) + bo[j];
                const float cn = sigmoidf_(fv) * cA[j] + sigmoidf_(iv) * tanhf_(jv);
                cA[j] = cn;
                hu[j] = f2bf(sigmoidf_(ov) * tanhf_(cn));
            }
            if (glo) {
                uint2v pk;
                pk[0] = (unsigned)hu[0] | ((unsigned)hu[1] << 16);
                pk[1] = (unsigned)hu[2] | ((unsigned)hu[3] << 16);
                store8_mall(hbuf + (size_t)(t + 1) * BH + hsoA, pk);
                if (t + PRE_AHEAD <= T_DIM)
                    store8_mall(hbuf + (size_t)(t + PRE_AHEAD) * BH + hsoA, sentv);
            }
        }

        if (t > 0) {
            // ---- P8: converge sweep B ----
            sweep_converge(hfrB, hrB);
            // ---- P9: chain B h-part MFMA ----
            #pragma unroll
            for (int k = 0; k < 16; ++k) {
                const unsigned short* wp = lds_w + ((size_t)((8 + k) * 2) * 64 + lane) * 8;
                aB0 = MFMA(*(const short8*)(wp +   0), hfrB[k], aB0, 0,0,0);
                aB1 = MFMA(*(const short8*)(wp + 512), hfrB[k], aB1, 0,0,0);
            }
        }

        // ---- P11: chain B update + store/arm ----
        {
            f32x4 p0, p1;
            #pragma unroll
            for (int j = 0; j < 4; ++j) {
                p0[j] = __shfl_xor(aB0[j], 32);
                p1[j] = __shfl_xor(aB1[j], 32);
            }
            unsigned short hu[4];
            #pragma unroll
            for (int j = 0; j < 4; ++j) {
                const float iv = (glo ? aB0[j] : p0[j]) + bi[j];
                const float jv = (glo ? p0[j] : aB0[j]) + bj[j];
                const float fv = (glo ? aB1[j] : p1[j]) + bf_[j];
                const float ov = (glo ? p1[j] : aB1[j]) + bo[j];
                const float cn = sigmoidf_(fv) * cB[j] + sigmoidf_(iv) * tanhf_(jv);
                cB[j] = cn;
                hu[j] = f2bf(sigmoidf_(ov) * tanhf_(cn));
            }
            if (glo) {
                uint2v pk;
                pk[0] = (unsigned)hu[0] | ((unsigned)hu[1] << 16);
                pk[1] = (unsigned)hu[2] | ((unsigned)hu[3] << 16);
                store8_mall(hbuf + (size_t)(t + 1) * BH + hsoB, pk);
                if (t + PRE_AHEAD <= T_DIM)
                    store8_mall(hbuf + (size_t)(t + PRE_AHEAD) * BH + hsoB, sentv);
            }
        }
        // Arm-before-visible ordering as R14: a consumer must first observe
        // h_{u-1}, which producers store after arming slot u -> cached sweeps
        // of slot u read sentinel-or-final-data, never stale replay data.
    }
}

// ---------------- final projection: out = h_last @ W_out + b_out ----------------
__global__ void __launch_bounds__(256)
proj_gemm(const unsigned short* __restrict__ h,   // [256][512] bf16 (slot T)
          const float* __restrict__ wout,         // [512][V]
          const float* __restrict__ bout,         // [V]
          float* __restrict__ out)                // [256][V]
{
    const int tid  = threadIdx.x;
    const int w    = tid >> 6;
    const int lane = tid & 63;
    const int lc   = lane & 15;
    const int lk   = lane >> 4;
    const int n0   = blockIdx.x * 128 + w * 32;

    f32x4 acc[16][2];
    #pragma unroll
    for (int mt = 0; mt < 16; ++mt) {
        acc[mt][0] = (f32x4){0.f,0.f,0.f,0.f};
        acc[mt][1] = (f32x4){0.f,0.f,0.f,0.f};
    }
    int ncl[2];
    ncl[0] = min(n0 + lc,      V_DIM - 1);
    ncl[1] = min(n0 + 16 + lc, V_DIM - 1);

    #pragma unroll 4
    for (int kt = 0; kt < 16; ++kt) {
        short8 bfr[2];
        #pragma unroll
        for (int nt = 0; nt < 2; ++nt) {
            #pragma unroll
            for (int j = 0; j < 8; ++j) {
                const int k = kt * 32 + lk * 8 + j;
                bfr[nt][j] = (short)f2bf(wout[(size_t)k * V_DIM + ncl[nt]]);
            }
        }
        #pragma unroll
        for (int mt = 0; mt < 16; ++mt) {
            const short8 a = *(const short8*)(h + (size_t)(mt * 16 + lc) * H_DIM
                                                + kt * 32 + lk * 8);
            acc[mt][0] = MFMA(a, bfr[0], acc[mt][0], 0,0,0);
            acc[mt][1] = MFMA(a, bfr[1], acc[mt][1], 0,0,0);
        }
    }

    #pragma unroll
    for (int nt = 0; nt < 2; ++nt) {
        const int n = n0 + nt * 16 + lc;
        if (n < V_DIM) {
            const float bb = bout[n];
            #pragma unroll
            for (int mt = 0; mt < 16; ++mt)
                #pragma unroll
                for (int j = 0; j < 4; ++j)
                    out[(size_t)(mt * 16 + lk * 4 + j) * V_DIM + n] = acc[mt][nt][j] + bb;
        }
    }
}

extern "C" void kernel_launch(void* const* d_in, const int* in_sizes, int n_in,
                              void* d_out, int out_size, void* d_ws, size_t ws_size,
                              hipStream_t stream) {
    const float* x    = (const float*)d_in[0];
    const float* wk   = (const float*)d_in[1];
    const float* bias = (const float*)d_in[2];
    const float* wout = (const float*)d_in[3];
    const float* bout = (const float*)d_in[4];
    float* out = (float*)d_out;

    // hbuf: (T+1) write-once slots of [B][H] bf16 ~= 64.3 MB (proven)
    unsigned short* hbuf = (unsigned short*)d_ws;

    // Arm slots 0..4 per call; slots >=5 JIT-armed by producers (step t arms
    // slot t+5), wiping stale prior-replay data (R8/R14-proven protocol).
    hipMemsetAsync(hbuf, 0x7F, (size_t)PRE_AHEAD * BH * 2, stream);

    hipFuncSetAttribute((const void*)lstm_persist,
                        hipFuncAttributeMaxDynamicSharedMemorySize, 48 * 1024);

    hipLaunchKernelGGL(lstm_persist, dim3(256), dim3(128), 48 * 1024, stream,
                       x, wk, bias, hbuf);
    // h_last = slot T; kernel-end release + dispatch acquire hand it to proj.
    hipLaunchKernelGGL(proj_gemm, dim3((V_DIM + 127) / 128), dim3(256), 0, stream,
                       hbuf + (size_t)T_DIM * BH, wout, bout, out);
}

// Round 16
// 1947.954 us; speedup vs baseline: 1.0629x; 1.0629x over previous
//
#include <hip/hip_runtime.h>
#include <hip/hip_bf16.h>

#define T_DIM 256
#define B_DIM 256
#define E_DIM 256
#define H_DIM 512
#define V_DIM 50257
#define BH    (B_DIM * H_DIM)          // elems per h slot
#define PRE_AHEAD 5                    // at step t, arm slot t+5
#define SENT  0x7F7F7F7Fu              // bf16 |h|<=1 can never be 0x7F7F

typedef __attribute__((ext_vector_type(8))) short short8;
typedef __attribute__((ext_vector_type(4))) float f32x4;
typedef __attribute__((ext_vector_type(4))) unsigned int uint4v;
typedef __attribute__((ext_vector_type(2))) unsigned int uint2v;

#define MFMA __builtin_amdgcn_mfma_f32_16x16x32_bf16

__device__ __forceinline__ unsigned short f2bf(float f) {
    union { float f; unsigned u; } v; v.f = f;
    unsigned r = v.u + 0x7FFFu + ((v.u >> 16) & 1u);
    return (unsigned short)(r >> 16);
}
__device__ __forceinline__ short cvt_bf(float f) { return (short)f2bf(f); }
__device__ __forceinline__ float sigmoidf_(float x) {
    return 1.0f / (1.0f + __expf(-x));
}
__device__ __forceinline__ float tanhf_(float x) {
    float xc = fminf(fmaxf(x, -15.0f), 15.0f);
    float e = __expf(2.0f * xc);
    return (e - 1.0f) / (e + 1.0f);
}

// Sweep discipline (R14-proven): first pass = C++ cached loads (L2-deduped,
// compiler-counted waits); escalation = asm sc0 sc1 (MALL truth) for pending
// fragments only. Stores/arms = asm sc0 sc1. Write-once slots + sentinel
// make cached first reads safe (sentinel-or-final-data, never stale).
__device__ __forceinline__ short8 load16_mall(const unsigned short* p) {
    short8 r;
    asm volatile("global_load_dwordx4 %0, %1, off sc0 sc1"
                 : "=v"(r) : "v"(p) : "memory");
    return r;
}
__device__ __forceinline__ void store8_mall(unsigned short* p, uint2v v) {
    asm volatile("global_store_dwordx2 %0, %1, off sc0 sc1"
                 :: "v"(p), "v"(v) : "memory");
}
__device__ __forceinline__ bool frag_ready(short8 v) {
    union { short8 s; uint4v u; } c; c.s = v;
    return (c.u[0] != SENT) & (c.u[1] != SENT) & (c.u[2] != SENT) & (c.u[3] != SENT);
}

// Escalation loop: asm MALL re-load of pending fragments until sentinel-free.
__device__ __forceinline__ void sweep_converge(short8 (&hfr)[16],
                                               const unsigned short* hr)
{
    unsigned pend = 0;
    #pragma unroll
    for (int k = 0; k < 16; ++k)
        pend |= frag_ready(hfr[k]) ? 0u : (1u << k);
    #pragma unroll 1
    while (!__all(pend == 0)) {
        #pragma unroll
        for (int k = 0; k < 16; ++k)
            if (pend & (1u << k)) hfr[k] = load16_mall(hr + k * 32);
        asm volatile("s_waitcnt vmcnt(0)" ::: "memory");
        __builtin_amdgcn_sched_barrier(0);
        unsigned np = 0;
        #pragma unroll
        for (int k = 0; k < 16; ++k)
            if (pend & (1u << k))
                np |= frag_ready(hfr[k]) ? 0u : (1u << k);
        pend = np;
    }
    __builtin_amdgcn_sched_barrier(0);
}

// ---------------- LSTM persistent kernel ----------------
// 256 blocks, 1/CU (48 KiB LDS). XCD-LOCALITY-AWARE roles (the R15 lesson):
//   pr = blk&3  -> chains bgA = pr, bgB = pr+4
//   hg = blk>>2 -> 8 hidden cols
// With round-robin dispatch XCD(blk) = blk%8, pair p's blocks land only on
// XCDs {p, p+4}: each XCD touches exactly TWO bg x-slices (L2-deduped), vs
// R15's all-8 scatter (539 MB HBM). Two independent recurrence chains are
// interleaved so each chain's sweep RTT hides under the other's compute.
// x prefetch for t+1 is issued at STEP START (readiness-free loads - early
// is strictly better; they land long before any escalation drain).
// Narrow-tile gate mapping + shfl_xor(32) exchange: R13/R15-proven.
__global__ void __launch_bounds__(128, 1)
lstm_persist(const float* __restrict__ x,
             const float* __restrict__ wk,
             const float* __restrict__ bias,
             unsigned short* __restrict__ hbuf)   // [T+1][B][H] bf16
{
    extern __shared__ unsigned short lds_w[];     // [48 frag][64 lane][8]
    const int tid = threadIdx.x;
    const int blk = blockIdx.x;
    const int pr  = blk & 3;                      // bg pair id
    const int hg  = blk >> 2;                     // 0..63
    const int hh  = hg * 8;

    // ---- preload weights into LDS as W^T fragments (once) ----
    // frag f = kt*2+n; lane l (c16=l&15); elem j:
    //   k = kt*32+(l>>4)*8+j, col = (n*2+(c16>>3))*512 + hh + (c16&7)
    for (int f = 0; f < 48; ++f) {
        const int kt = f >> 1, n = f & 1;
        for (int idx = tid; idx < 512; idx += 128) {
            const int l   = idx & 63;
            const int j   = idx >> 6;
            const int c16 = l & 15;
            const int k   = kt * 32 + (l >> 4) * 8 + j;
            const int col = (n * 2 + (c16 >> 3)) * 512 + hh + (c16 & 7);
            lds_w[(f * 64 + l) * 8 + j] = f2bf(wk[(size_t)k * 2048 + col]);
        }
    }
    __syncthreads();

    const int w    = tid >> 6;        // wave: rows [bb + w*16, +16) per chain
    const int lane = tid & 63;
    const int lc   = lane & 15;
    const int lk   = lane >> 4;
    const int hb4  = (lk & 1) * 4;    // lane's hcol base (0 or 4)
    const bool glo = (lane & 32) == 0;  // holds gates {i,f}; partner {j,o}

    const f32x4 bi  = *(const f32x4*)(bias + 0 * 512 + hh + hb4);
    const f32x4 bj  = *(const f32x4*)(bias + 1 * 512 + hh + hb4);
    f32x4       bf_ = *(const f32x4*)(bias + 2 * 512 + hh + hb4);
    const f32x4 bo  = *(const f32x4*)(bias + 3 * 512 + hh + hb4);
    bf_ = bf_ + 1.0f;                                  // FORGET_BIAS

    const int arowA = pr * 32       + w * 16 + lc;     // chain A batch row
    const int arowB = (pr + 4) * 32 + w * 16 + lc;     // chain B batch row
    const float* xrowA = x + (size_t)arowA * E_DIM + lk * 8;
    const float* xrowB = x + (size_t)arowB * E_DIM + lk * 8;
    const size_t hroA = (size_t)arowA * H_DIM + lk * 8;
    const size_t hroB = (size_t)arowB * H_DIM + lk * 8;
    const size_t hsoA = (size_t)arowA * H_DIM + hh + hb4;
    const size_t hsoB = (size_t)arowB * H_DIM + hh + hb4;

    f32x4 cA = {0.f,0.f,0.f,0.f}, cB = cA;

    // ---- x_0 for both chains ----
    f32x4 xregA[16], xregB[16];
    #pragma unroll
    for (int k = 0; k < 8; ++k) {
        xregA[2*k]   = *(const f32x4*)(xrowA + k * 32);
        xregA[2*k+1] = *(const f32x4*)(xrowA + k * 32 + 4);
        xregB[2*k]   = *(const f32x4*)(xrowB + k * 32);
        xregB[2*k+1] = *(const f32x4*)(xrowB + k * 32 + 4);
    }

    const uint2v sentv = {SENT, SENT};

    for (int t = 0; t < T_DIM; ++t) {
        const unsigned short* hrA = hbuf + (size_t)t * BH + hroA;
        const unsigned short* hrB = hbuf + (size_t)t * BH + hroB;
        short8 hfrA[16], hfrB[16];

        // ---- P0: consume current x into packed bf16 (frees xreg), then
        //          IMMEDIATELY issue next-step x prefetch for both chains.
        //          Prefetches are readiness-free: early issue is strictly
        //          better; they land before any escalation drain (R15 bug).
        short8 apkA[8], apkB[8];
        #pragma unroll
        for (int kt = 0; kt < 8; ++kt) {
            const f32x4 loA = xregA[2*kt], hiA = xregA[2*kt+1];
            short8 a;
            a[0]=cvt_bf(loA[0]); a[1]=cvt_bf(loA[1]); a[2]=cvt_bf(loA[2]); a[3]=cvt_bf(loA[3]);
            a[4]=cvt_bf(hiA[0]); a[5]=cvt_bf(hiA[1]); a[6]=cvt_bf(hiA[2]); a[7]=cvt_bf(hiA[3]);
            apkA[kt] = a;
            const f32x4 loB = xregB[2*kt], hiB = xregB[2*kt+1];
            short8 b;
            b[0]=cvt_bf(loB[0]); b[1]=cvt_bf(loB[1]); b[2]=cvt_bf(loB[2]); b[3]=cvt_bf(loB[3]);
            b[4]=cvt_bf(hiB[0]); b[5]=cvt_bf(hiB[1]); b[6]=cvt_bf(hiB[2]); b[7]=cvt_bf(hiB[3]);
            apkB[kt] = b;
        }
        if (t + 1 < T_DIM) {
            const float* xnA = xrowA + (size_t)(t + 1) * (B_DIM * E_DIM);
            const float* xnB = xrowB + (size_t)(t + 1) * (B_DIM * E_DIM);
            #pragma unroll
            for (int k = 0; k < 8; ++k) {
                xregA[2*k]   = *(const f32x4*)(xnA + k * 32);
                xregA[2*k+1] = *(const f32x4*)(xnA + k * 32 + 4);
                xregB[2*k]   = *(const f32x4*)(xnB + k * 32);
                xregB[2*k+1] = *(const f32x4*)(xnB + k * 32 + 4);
            }
        }

        // ---- P1: chain A x-part MFMA ----
        f32x4 aA0 = {0.f,0.f,0.f,0.f}, aA1 = aA0;
        #pragma unroll
        for (int kt = 0; kt < 8; ++kt) {
            const unsigned short* wp = lds_w + ((size_t)(kt * 2) * 64 + lane) * 8;
            aA0 = MFMA(*(const short8*)(wp +   0), apkA[kt], aA0, 0,0,0);
            aA1 = MFMA(*(const short8*)(wp + 512), apkA[kt], aA1, 0,0,0);
        }

        // ---- P2: issue sweep A (pinned after P1) ----
        if (t > 0) {
            __builtin_amdgcn_sched_barrier(0);
            #pragma unroll
            for (int k = 0; k < 16; ++k)
                hfrA[k] = *(const short8*)(hrA + k * 32);
        }

        // ---- P3: chain B x-part MFMA (hides sweep A RTT) ----
        f32x4 aB0 = {0.f,0.f,0.f,0.f}, aB1 = aB0;
        #pragma unroll
        for (int kt = 0; kt < 8; ++kt) {
            const unsigned short* wp = lds_w + ((size_t)(kt * 2) * 64 + lane) * 8;
            aB0 = MFMA(*(const short8*)(wp +   0), apkB[kt], aB0, 0,0,0);
            aB1 = MFMA(*(const short8*)(wp + 512), apkB[kt], aB1, 0,0,0);
        }

        if (t > 0) {
            // ---- P4: converge sweep A; P5: chain A h-part MFMA ----
            sweep_converge(hfrA, hrA);
            #pragma unroll
            for (int k = 0; k < 16; ++k) {
                const unsigned short* wp = lds_w + ((size_t)((8 + k) * 2) * 64 + lane) * 8;
                aA0 = MFMA(*(const short8*)(wp +   0), hfrA[k], aA0, 0,0,0);
                aA1 = MFMA(*(const short8*)(wp + 512), hfrA[k], aA1, 0,0,0);
            }
            // ---- P6: issue sweep B (pinned late) ----
            __builtin_amdgcn_sched_barrier(0);
            #pragma unroll
            for (int k = 0; k < 16; ++k)
                hfrB[k] = *(const short8*)(hrB + k * 32);
        }

        // ---- P7: chain A update + fire-and-forget store/arm ----
        {
            f32x4 p0, p1;
            #pragma unroll
            for (int j = 0; j < 4; ++j) {
                p0[j] = __shfl_xor(aA0[j], 32);
                p1[j] = __shfl_xor(aA1[j], 32);
            }
            unsigned short hu[4];
            #pragma unroll
            for (int j = 0; j < 4; ++j) {
                const float iv = (glo ? aA0[j] : p0[j]) + bi[j];
                const float jv = (glo ? p0[j] : aA0[j]) + bj[j];
                const float fv = (glo ? aA1[j] : p1[j]) + bf_[j];
                const float ov = (glo ? p1[j] : aA1[j]) + bo[j];
                const float cn = sigmoidf_(fv) * cA[j] + sigmoidf_(iv) * tanhf_(jv);
                cA[j] = cn;
                hu[j] = f2bf(sigmoidf_(ov) * tanhf_(cn));
            }
            if (glo) {
                uint2v pk;
                pk[0] = (unsigned)hu[0] | ((unsigned)hu[1] << 16);
                pk[1] = (unsigned)hu[2] | ((unsigned)hu[3] << 16);
                store8_mall(hbuf + (size_t)(t + 1) * BH + hsoA, pk);
                if (t + PRE_AHEAD <= T_DIM)
                    store8_mall(hbuf + (size_t)(t + PRE_AHEAD) * BH + hsoA, sentv);
            }
        }

        if (t > 0) {
            // ---- P8: converge sweep B; P9: chain B h-part MFMA ----
            sweep_converge(hfrB, hrB);
            #pragma unroll
            for (int k = 0; k < 16; ++k) {
                const unsigned short* wp = lds_w + ((size_t)((8 + k) * 2) * 64 + lane) * 8;
                aB0 = MFMA(*(const short8*)(wp +   0), hfrB[k], aB0, 0,0,0);
                aB1 = MFMA(*(const short8*)(wp + 512), hfrB[k], aB1, 0,0,0);
            }
        }

        // ---- P10: chain B update + store/arm ----
        {
            f32x4 p0, p1;
            #pragma unroll
            for (int j = 0; j < 4; ++j) {
                p0[j] = __shfl_xor(aB0[j], 32);
                p1[j] = __shfl_xor(aB1[j], 32);
            }
            unsigned short hu[4];
            #pragma unroll
            for (int j = 0; j < 4; ++j) {
                const float iv = (glo ? aB0[j] : p0[j]) + bi[j];
                const float jv = (glo ? p0[j] : aB0[j]) + bj[j];
                const float fv = (glo ? aB1[j] : p1[j]) + bf_[j];
                const float ov = (glo ? p1[j] : aB1[j]) + bo[j];
                const float cn = sigmoidf_(fv) * cB[j] + sigmoidf_(iv) * tanhf_(jv);
                cB[j] = cn;
                hu[j] = f2bf(sigmoidf_(ov) * tanhf_(cn));
            }
            if (glo) {
                uint2v pk;
                pk[0] = (unsigned)hu[0] | ((unsigned)hu[1] << 16);
                pk[1] = (unsigned)hu[2] | ((unsigned)hu[3] << 16);
                store8_mall(hbuf + (size_t)(t + 1) * BH + hsoB, pk);
                if (t + PRE_AHEAD <= T_DIM)
                    store8_mall(hbuf + (size_t)(t + PRE_AHEAD) * BH + hsoB, sentv);
            }
        }
        // Arm-before-visible ordering (R14-proven): a consumer must first
        // observe h_{u-1}, stored after slot u's arm -> cached sweeps read
        // sentinel-or-final-data, never stale replay data.
    }
}

// ---------------- final projection: out = h_last @ W_out + b_out ----------------
__global__ void __launch_bounds__(256)
proj_gemm(const unsigned short* __restrict__ h,   // [256][512] bf16 (slot T)
          const float* __restrict__ wout,         // [512][V]
          const float* __restrict__ bout,         // [V]
          float* __restrict__ out)                // [256][V]
{
    const int tid  = threadIdx.x;
    const int w    = tid >> 6;
    const int lane = tid & 63;
    const int lc   = lane & 15;
    const int lk   = lane >> 4;
    const int n0   = blockIdx.x * 128 + w * 32;

    f32x4 acc[16][2];
    #pragma unroll
    for (int mt = 0; mt < 16; ++mt) {
        acc[mt][0] = (f32x4){0.f,0.f,0.f,0.f};
        acc[mt][1] = (f32x4){0.f,0.f,0.f,0.f};
    }
    int ncl[2];
    ncl[0] = min(n0 + lc,      V_DIM - 1);
    ncl[1] = min(n0 + 16 + lc, V_DIM - 1);

    #pragma unroll 4
    for (int kt = 0; kt < 16; ++kt) {
        short8 bfr[2];
        #pragma unroll
        for (int nt = 0; nt < 2; ++nt) {
            #pragma unroll
            for (int j = 0; j < 8; ++j) {
                const int k = kt * 32 + lk * 8 + j;
                bfr[nt][j] = (short)f2bf(wout[(size_t)k * V_DIM + ncl[nt]]);
            }
        }
        #pragma unroll
        for (int mt = 0; mt < 16; ++mt) {
            const short8 a = *(const short8*)(h + (size_t)(mt * 16 + lc) * H_DIM
                                                + kt * 32 + lk * 8);
            acc[mt][0] = MFMA(a, bfr[0], acc[mt][0], 0,0,0);
            acc[mt][1] = MFMA(a, bfr[1], acc[mt][1], 0,0,0);
        }
    }

    #pragma unroll
    for (int nt = 0; nt < 2; ++nt) {
        const int n = n0 + nt * 16 + lc;
        if (n < V_DIM) {
            const float bb = bout[n];
            #pragma unroll
            for (int mt = 0; mt < 16; ++mt)
                #pragma unroll
                for (int j = 0; j < 4; ++j)
                    out[(size_t)(mt * 16 + lk * 4 + j) * V_DIM + n] = acc[mt][nt][j] + bb;
        }
    }
}

extern "C" void kernel_launch(void* const* d_in, const int* in_sizes, int n_in,
                              void* d_out, int out_size, void* d_ws, size_t ws_size,
                              hipStream_t stream) {
    const float* x    = (const float*)d_in[0];
    const float* wk   = (const float*)d_in[1];
    const float* bias = (const float*)d_in[2];
    const float* wout = (const float*)d_in[3];
    const float* bout = (const float*)d_in[4];
    float* out = (float*)d_out;

    // hbuf: (T+1) write-once slots of [B][H] bf16 ~= 64.3 MB (proven)
    unsigned short* hbuf = (unsigned short*)d_ws;

    // Arm slots 0..4 per call; slots >=5 JIT-armed by producers (step t arms
    // slot t+5), wiping stale prior-replay data (R8/R14-proven protocol).
    hipMemsetAsync(hbuf, 0x7F, (size_t)PRE_AHEAD * BH * 2, stream);

    hipFuncSetAttribute((const void*)lstm_persist,
                        hipFuncAttributeMaxDynamicSharedMemorySize, 48 * 1024);

    hipLaunchKernelGGL(lstm_persist, dim3(256), dim3(128), 48 * 1024, stream,
                       x, wk, bias, hbuf);
    // h_last = slot T; kernel-end release + dispatch acquire hand it to proj.
    hipLaunchKernelGGL(proj_gemm, dim3((V_DIM + 127) / 128), dim3(256), 0, stream,
                       hbuf + (size_t)T_DIM * BH, wout, bout, out);
}